// Round 4
// baseline (241.688 us; speedup 1.0000x reference)
//
#include <hip/hip_runtime.h>
#include <cstdint>
#include <cstddef>

// Fused Swin-style window attention for MI355X (gfx950), round 3 (resubmit; R3 bench
// died on an unresponsive container before producing any signal).
// B=4096 windows, N=64 tokens, C=128, H=4 heads, hd=32.
// One block per window, 4 waves (wave = head). bf16 x-tile staged in LDS
// (native cvt_pk), two-sub-pass qkv to cap register pressure (<=128 for
// 4 blocks/CU), 2 barriers, separate attn-out LDS buffer, exp2 softmax.

typedef float f32x4 __attribute__((ext_vector_type(4)));
typedef __bf16 bf16x8 __attribute__((ext_vector_type(8)));
typedef short s16x4 __attribute__((ext_vector_type(4)));
typedef unsigned short u16x8 __attribute__((ext_vector_type(8)));
typedef unsigned short u16x4 __attribute__((ext_vector_type(4)));

__device__ __forceinline__ unsigned short bfs(float f) {
  return __builtin_bit_cast(unsigned short, (__bf16)f);  // HW RNE cvt
}
__device__ __forceinline__ unsigned pk2n(float a, float b) {
  return (unsigned)bfs(a) | ((unsigned)bfs(b) << 16);
}
__device__ __forceinline__ u16x4 pack4(f32x4 v) {
  u16x4 r; r[0] = bfs(v[0]); r[1] = bfs(v[1]); r[2] = bfs(v[2]); r[3] = bfs(v[3]);
  return r;
}
__device__ __forceinline__ f32x4 bf4up(u16x4 v) {
  f32x4 r;
  r[0] = __builtin_bit_cast(float, (unsigned)v[0] << 16);
  r[1] = __builtin_bit_cast(float, (unsigned)v[1] << 16);
  r[2] = __builtin_bit_cast(float, (unsigned)v[2] << 16);
  r[3] = __builtin_bit_cast(float, (unsigned)v[3] << 16);
  return r;
}
__device__ __forceinline__ f32x4 mfma32(u16x8 a, u16x8 b, f32x4 c) {
  return __builtin_amdgcn_mfma_f32_16x16x32_bf16(
      __builtin_bit_cast(bf16x8, a), __builtin_bit_cast(bf16x8, b), c, 0, 0, 0);
}
__device__ __forceinline__ f32x4 mfma16(u16x4 a, u16x4 b, f32x4 c) {
  return __builtin_amdgcn_mfma_f32_16x16x16bf16_1k(
      __builtin_bit_cast(s16x4, a), __builtin_bit_cast(s16x4, b), c, 0, 0, 0);
}

// ---------------- prep: weights^T -> bf16, rel-pos bias -> bf16 frag layout ----------
// ws: [0,98304)        wqkv_t bf16 [384 cols][128 k]   (Q cols scaled by log2e/sqrt(hd))
//     [98304,131072)   wproj_t bf16 [128 cols][128 k]
//     [131072,163840)  bias bf16 [h][mk][nq][lane][i]  (S^T frag layout, * log2e)
__global__ void prep_kernel(const float* __restrict__ wqkv, const float* __restrict__ wproj,
                            const float* __restrict__ btab,
                            unsigned short* __restrict__ wqkvt,
                            unsigned short* __restrict__ wprojt,
                            unsigned short* __restrict__ biasbf) {
  int t = blockIdx.x * 256 + threadIdx.x;
  if (t < 49152) {
    int c = t >> 7, k = t & 127;
    float v = wqkv[k * 384 + c];
    if (c < 128) v *= 0.25503486f;  // log2(e)/sqrt(32)
    wqkvt[t] = bfs(v);
  } else if (t < 65536) {
    int t2 = t - 49152;
    int c = t2 >> 7, k = t2 & 127;
    wprojt[t2] = bfs(wproj[k * 128 + c]);
  } else if (t < 81920) {
    int t3 = t - 65536;
    int i = t3 & 3, lane = (t3 >> 2) & 63, nq = (t3 >> 8) & 3, mk = (t3 >> 10) & 3, h = t3 >> 12;
    int key = mk * 16 + ((lane >> 4) << 2) + i;  // S^T row (C-layout)
    int q   = nq * 16 + (lane & 15);             // S^T col
    int idx = ((q >> 3) - (key >> 3) + 7) * 15 + ((q & 7) - (key & 7) + 7);
    biasbf[t3] = bfs(btab[idx * 4 + h] * 1.4426950408889634f);
  }
}

// ---------------- fused attention: 1 window / block ----------------
__global__ __launch_bounds__(256, 4) void attn_kernel(
    const float* __restrict__ x, const unsigned short* __restrict__ wqkvt,
    const unsigned short* __restrict__ wprojt, const unsigned short* __restrict__ biasbf,
    const float* __restrict__ bproj, float* __restrict__ out) {
  __shared__ char lds[32768];
  char* xs = lds;           // bf16 x tile [64 tok][128 c], byte-XOR swizzled
  char* ao = lds + 16384;   // bf16 attn-out tile, same swizzle
  const int tid = threadIdx.x;
  const int lane = tid & 63;
  const int h = tid >> 6;   // wave = head
  const int g = lane >> 4;
  const int q15 = lane & 15;
  const int rs = (q15 & 7) << 4;  // read swizzle; row%8 == q15%8 for our reads
  const size_t wbase = (size_t)blockIdx.x * 8192;
  const f32x4 zero4 = {0.f, 0.f, 0.f, 0.f};

  // ---- stage x: f32 -> bf16 (native cvt_pk), swizzled ----
  {
    const int row = tid >> 2;
    const int cb = (tid & 3) * 32;
    const float* xp = x + wbase + row * 128 + cb;
#pragma unroll
    for (int u = 0; u < 4; ++u) {
      f32x4 a = *(const f32x4*)(xp + u * 8);
      f32x4 b = *(const f32x4*)(xp + u * 8 + 4);
      uint4 p;
      p.x = pk2n(a[0], a[1]); p.y = pk2n(a[2], a[3]);
      p.z = pk2n(b[0], b[1]); p.w = pk2n(b[2], b[3]);
      int byte = row * 256 + (((cb * 2) + u * 16) ^ ((row & 7) << 4));
      *(uint4*)(xs + byte) = p;
    }
  }
  __syncthreads();  // A: x tile visible

  const char* wqb = (const char*)wqkvt;

  // ---- sub-pass A: Q^T, K^T = Wqk^T · x^T ----
  f32x4 qt[2][4], kt[2][4];
#pragma unroll
  for (int m = 0; m < 2; ++m)
#pragma unroll
    for (int t = 0; t < 4; ++t) { qt[m][t] = zero4; kt[m][t] = zero4; }
#pragma unroll
  for (int ks = 0; ks < 4; ++ks) {
    u16x8 xb[4];
#pragma unroll
    for (int t = 0; t < 4; ++t)
      xb[t] = *(const u16x8*)(xs + (t * 16 + q15) * 256 + ((ks * 64 + g * 16) ^ rs));
    const int kb = ks * 64 + g * 16;
    u16x8 wq[2], wk[2];
#pragma unroll
    for (int m = 0; m < 2; ++m) {
      int col = h * 32 + m * 16 + q15;
      wq[m] = *(const u16x8*)(wqb + (size_t)col * 256 + kb);
      wk[m] = *(const u16x8*)(wqb + (size_t)(col + 128) * 256 + kb);
    }
#pragma unroll
    for (int m = 0; m < 2; ++m)
#pragma unroll
      for (int t = 0; t < 4; ++t) {
        qt[m][t] = mfma32(wq[m], xb[t], qt[m][t]);  // [c][tok]
        kt[m][t] = mfma32(wk[m], xb[t], kt[m][t]);
      }
  }
  u16x4 qp[2][4], kp[2][4];
#pragma unroll
  for (int m = 0; m < 2; ++m)
#pragma unroll
    for (int t = 0; t < 4; ++t) { qp[m][t] = pack4(qt[m][t]); kp[m][t] = pack4(kt[m][t]); }

  // ---- sub-pass B: V = x · Wv (re-read xs; frees qkv accs first) ----
  f32x4 vv[4][2];
#pragma unroll
  for (int t = 0; t < 4; ++t) { vv[t][0] = zero4; vv[t][1] = zero4; }
#pragma unroll
  for (int ks = 0; ks < 4; ++ks) {
    u16x8 xb[4];
#pragma unroll
    for (int t = 0; t < 4; ++t)
      xb[t] = *(const u16x8*)(xs + (t * 16 + q15) * 256 + ((ks * 64 + g * 16) ^ rs));
    const int kb = ks * 64 + g * 16;
    u16x8 wv[2];
#pragma unroll
    for (int n = 0; n < 2; ++n)
      wv[n] = *(const u16x8*)(wqb + (size_t)(h * 32 + n * 16 + q15 + 256) * 256 + kb);
#pragma unroll
    for (int t = 0; t < 4; ++t)
#pragma unroll
      for (int n = 0; n < 2; ++n)
        vv[t][n] = mfma32(xb[t], wv[n], vv[t][n]);  // [tok][d]
  }
  u16x4 vp[4][2];
#pragma unroll
  for (int t = 0; t < 4; ++t) { vp[t][0] = pack4(vv[t][0]); vp[t][1] = pack4(vv[t][1]); }

  // ---- S^T = K·Q^T + bias (bias loaded straight into accumulators, L2-hot) ----
  f32x4 st[4][4];
  const u16x4* bb = (const u16x4*)biasbf;
#pragma unroll
  for (int mk = 0; mk < 4; ++mk)
#pragma unroll
    for (int nq = 0; nq < 4; ++nq)
      st[mk][nq] = bf4up(bb[((h * 4 + mk) * 4 + nq) * 64 + lane]);
#pragma unroll
  for (int ks2 = 0; ks2 < 2; ++ks2)
#pragma unroll
    for (int mk = 0; mk < 4; ++mk)
#pragma unroll
      for (int nq = 0; nq < 4; ++nq)
        st[mk][nq] = mfma16(kp[ks2][mk], qp[ks2][nq], st[mk][nq]);

  // ---- softmax over keys (logits pre-scaled by log2e; no max-subtract needed) ----
  float rc[4];
#pragma unroll
  for (int nq = 0; nq < 4; ++nq) {
    float s = 0.f;
#pragma unroll
    for (int mk = 0; mk < 4; ++mk)
#pragma unroll
      for (int i = 0; i < 4; ++i) {
        float e = exp2f(st[mk][nq][i]);
        st[mk][nq][i] = e;
        s += e;
      }
    s += __shfl_xor(s, 16);
    s += __shfl_xor(s, 32);
    rc[nq] = __builtin_amdgcn_rcpf(s);
  }
  u16x4 pp[4][4];
#pragma unroll
  for (int mk = 0; mk < 4; ++mk)
#pragma unroll
    for (int nq = 0; nq < 4; ++nq) pp[mk][nq] = pack4(st[mk][nq]);

  // ---- out^T = V^T · P^T ----
  f32x4 ot[2][4];
#pragma unroll
  for (int md = 0; md < 2; ++md)
#pragma unroll
    for (int nq = 0; nq < 4; ++nq) ot[md][nq] = zero4;
#pragma unroll
  for (int ks = 0; ks < 4; ++ks)
#pragma unroll
    for (int md = 0; md < 2; ++md)
#pragma unroll
      for (int nq = 0; nq < 4; ++nq)
        ot[md][nq] = mfma16(vp[ks][md], pp[ks][nq], ot[md][nq]);

  // ---- stage attn-out bf16 into ao (own region; no WAR on xs) ----
#pragma unroll
  for (int md = 0; md < 2; ++md)
#pragma unroll
    for (int nq = 0; nq < 4; ++nq) {
      int tok = nq * 16 + q15;
      int cb = (h * 64 + md * 32 + g * 8) ^ rs;  // tok&7 == q15&7
      uint2 w2;
      w2.x = pk2n(ot[md][nq][0] * rc[nq], ot[md][nq][1] * rc[nq]);
      w2.y = pk2n(ot[md][nq][2] * rc[nq], ot[md][nq][3] * rc[nq]);
      *(uint2*)(ao + tok * 256 + cb) = w2;
    }

  // ---- prefetch proj weights/bias while waiting at the barrier ----
  u16x8 wp[4][2];
  const char* wpb = (const char*)wprojt;
#pragma unroll
  for (int ks = 0; ks < 4; ++ks)
#pragma unroll
    for (int n = 0; n < 2; ++n)
      wp[ks][n] = *(const u16x8*)(wpb + (size_t)(h * 32 + n * 16 + q15) * 256 + ks * 64 + g * 16);
  float bvs0 = bproj[h * 32 + q15];
  float bvs1 = bproj[h * 32 + 16 + q15];
  __syncthreads();  // C: attn-out complete

  // ---- proj GEMM: out = ao · Wproj + b ----
  f32x4 pr[4][2];
#pragma unroll
  for (int t = 0; t < 4; ++t) { pr[t][0] = zero4; pr[t][1] = zero4; }
#pragma unroll
  for (int ks = 0; ks < 4; ++ks) {
    u16x8 axb[4];
#pragma unroll
    for (int t = 0; t < 4; ++t)
      axb[t] = *(const u16x8*)(ao + (t * 16 + q15) * 256 + ((ks * 64 + g * 16) ^ rs));
#pragma unroll
    for (int t = 0; t < 4; ++t)
#pragma unroll
      for (int n = 0; n < 2; ++n)
        pr[t][n] = mfma32(axb[t], wp[ks][n], pr[t][n]);  // [tok][col]
  }
  float* op = out + wbase;
#pragma unroll
  for (int n = 0; n < 2; ++n) {
    float bv = n ? bvs1 : bvs0;
#pragma unroll
    for (int t = 0; t < 4; ++t)
#pragma unroll
      for (int i = 0; i < 4; ++i)
        op[(size_t)(t * 16 + g * 4 + i) * 128 + h * 32 + n * 16 + q15] = pr[t][n][i] + bv;
  }
}

extern "C" void kernel_launch(void* const* d_in, const int* in_sizes, int n_in,
                              void* d_out, int out_size, void* d_ws, size_t ws_size,
                              hipStream_t stream) {
  const float* x     = (const float*)d_in[0];
  const float* wqkv  = (const float*)d_in[1];
  const float* wproj = (const float*)d_in[2];
  const float* bproj = (const float*)d_in[3];
  const float* btab  = (const float*)d_in[4];
  char* ws = (char*)d_ws;
  unsigned short* wqkvt  = (unsigned short*)ws;             // 98304 B
  unsigned short* wprojt = (unsigned short*)(ws + 98304);   // 32768 B
  unsigned short* biasbf = (unsigned short*)(ws + 131072);  // 32768 B

  prep_kernel<<<320, 256, 0, stream>>>(wqkv, wproj, btab, wqkvt, wprojt, biasbf);
  attn_kernel<<<4096, 256, 0, stream>>>(x, wqkvt, wprojt, biasbf, bproj, (float*)d_out);
}

// Round 6
// 110.796 us; speedup vs baseline: 2.1814x; 2.1814x over previous
//
#include <hip/hip_runtime.h>
#include <cstdint>
#include <cstddef>

// Fused Swin-style window attention for MI355X (gfx950), round 5 (resubmit; the
// R5 bench died on an unresponsive container before producing any signal).
// R4 lesson: launch_bounds(256,4) forced a 128-reg cap -> 64 VGPR + spills
// (FETCH +148MB, WRITE +490MB scratch traffic). R5 = same structure with
// (256,2) cap (no spill) + transposed proj GEMM for f32x4 output stores.

typedef float f32x4 __attribute__((ext_vector_type(4)));
typedef __bf16 bf16x8 __attribute__((ext_vector_type(8)));
typedef short s16x4 __attribute__((ext_vector_type(4)));
typedef unsigned short u16x8 __attribute__((ext_vector_type(8)));
typedef unsigned short u16x4 __attribute__((ext_vector_type(4)));

__device__ __forceinline__ unsigned short bfs(float f) {
  return __builtin_bit_cast(unsigned short, (__bf16)f);  // HW RNE cvt
}
__device__ __forceinline__ unsigned pk2n(float a, float b) {
  return (unsigned)bfs(a) | ((unsigned)bfs(b) << 16);
}
__device__ __forceinline__ u16x4 pack4(f32x4 v) {
  u16x4 r; r[0] = bfs(v[0]); r[1] = bfs(v[1]); r[2] = bfs(v[2]); r[3] = bfs(v[3]);
  return r;
}
__device__ __forceinline__ f32x4 bf4up(u16x4 v) {
  f32x4 r;
  r[0] = __builtin_bit_cast(float, (unsigned)v[0] << 16);
  r[1] = __builtin_bit_cast(float, (unsigned)v[1] << 16);
  r[2] = __builtin_bit_cast(float, (unsigned)v[2] << 16);
  r[3] = __builtin_bit_cast(float, (unsigned)v[3] << 16);
  return r;
}
__device__ __forceinline__ f32x4 mfma32(u16x8 a, u16x8 b, f32x4 c) {
  return __builtin_amdgcn_mfma_f32_16x16x32_bf16(
      __builtin_bit_cast(bf16x8, a), __builtin_bit_cast(bf16x8, b), c, 0, 0, 0);
}
__device__ __forceinline__ f32x4 mfma16(u16x4 a, u16x4 b, f32x4 c) {
  return __builtin_amdgcn_mfma_f32_16x16x16bf16_1k(
      __builtin_bit_cast(s16x4, a), __builtin_bit_cast(s16x4, b), c, 0, 0, 0);
}

// ---------------- prep: weights^T -> bf16, rel-pos bias -> bf16 frag layout ----------
// ws: [0,98304)        wqkv_t bf16 [384 cols][128 k]   (Q cols scaled by log2e/sqrt(hd))
//     [98304,131072)   wproj_t bf16 [128 cols][128 k]
//     [131072,163840)  bias bf16 [h][mk][nq][lane][i]  (S^T frag layout, * log2e)
__global__ void prep_kernel(const float* __restrict__ wqkv, const float* __restrict__ wproj,
                            const float* __restrict__ btab,
                            unsigned short* __restrict__ wqkvt,
                            unsigned short* __restrict__ wprojt,
                            unsigned short* __restrict__ biasbf) {
  int t = blockIdx.x * 256 + threadIdx.x;
  if (t < 49152) {
    int c = t >> 7, k = t & 127;
    float v = wqkv[k * 384 + c];
    if (c < 128) v *= 0.25503486f;  // log2(e)/sqrt(32)
    wqkvt[t] = bfs(v);
  } else if (t < 65536) {
    int t2 = t - 49152;
    int c = t2 >> 7, k = t2 & 127;
    wprojt[t2] = bfs(wproj[k * 128 + c]);
  } else if (t < 81920) {
    int t3 = t - 65536;
    int i = t3 & 3, lane = (t3 >> 2) & 63, nq = (t3 >> 8) & 3, mk = (t3 >> 10) & 3, h = t3 >> 12;
    int key = mk * 16 + ((lane >> 4) << 2) + i;  // S^T row (C-layout)
    int q   = nq * 16 + (lane & 15);             // S^T col
    int idx = ((q >> 3) - (key >> 3) + 7) * 15 + ((q & 7) - (key & 7) + 7);
    biasbf[t3] = bfs(btab[idx * 4 + h] * 1.4426950408889634f);
  }
}

// ---------------- fused attention: 1 window / block ----------------
__global__ __launch_bounds__(256, 2) void attn_kernel(
    const float* __restrict__ x, const unsigned short* __restrict__ wqkvt,
    const unsigned short* __restrict__ wprojt, const unsigned short* __restrict__ biasbf,
    const float* __restrict__ bproj, float* __restrict__ out) {
  __shared__ char lds[32768];
  char* xs = lds;           // bf16 x tile [64 tok][128 c], byte-XOR swizzled
  char* ao = lds + 16384;   // bf16 attn-out tile, same swizzle
  const int tid = threadIdx.x;
  const int lane = tid & 63;
  const int h = tid >> 6;   // wave = head
  const int g = lane >> 4;
  const int q15 = lane & 15;
  const int rs = (q15 & 7) << 4;  // read swizzle; row%8 == q15%8 for our reads
  const size_t wbase = (size_t)blockIdx.x * 8192;
  const f32x4 zero4 = {0.f, 0.f, 0.f, 0.f};

  // ---- stage x: f32 -> bf16 (native cvt_pk), swizzled ----
  {
    const int row = tid >> 2;
    const int cb = (tid & 3) * 32;
    const float* xp = x + wbase + row * 128 + cb;
#pragma unroll
    for (int u = 0; u < 4; ++u) {
      f32x4 a = *(const f32x4*)(xp + u * 8);
      f32x4 b = *(const f32x4*)(xp + u * 8 + 4);
      uint4 p;
      p.x = pk2n(a[0], a[1]); p.y = pk2n(a[2], a[3]);
      p.z = pk2n(b[0], b[1]); p.w = pk2n(b[2], b[3]);
      int byte = row * 256 + (((cb * 2) + u * 16) ^ ((row & 7) << 4));
      *(uint4*)(xs + byte) = p;
    }
  }
  __syncthreads();  // A: x tile visible

  const char* wqb = (const char*)wqkvt;

  // ---- sub-pass A: Q^T, K^T = Wqk^T · x^T ----
  f32x4 qt[2][4], kt[2][4];
#pragma unroll
  for (int m = 0; m < 2; ++m)
#pragma unroll
    for (int t = 0; t < 4; ++t) { qt[m][t] = zero4; kt[m][t] = zero4; }
#pragma unroll
  for (int ks = 0; ks < 4; ++ks) {
    u16x8 xb[4];
#pragma unroll
    for (int t = 0; t < 4; ++t)
      xb[t] = *(const u16x8*)(xs + (t * 16 + q15) * 256 + ((ks * 64 + g * 16) ^ rs));
    const int kb = ks * 64 + g * 16;
    u16x8 wq[2], wk[2];
#pragma unroll
    for (int m = 0; m < 2; ++m) {
      int col = h * 32 + m * 16 + q15;
      wq[m] = *(const u16x8*)(wqb + (size_t)col * 256 + kb);
      wk[m] = *(const u16x8*)(wqb + (size_t)(col + 128) * 256 + kb);
    }
#pragma unroll
    for (int m = 0; m < 2; ++m)
#pragma unroll
      for (int t = 0; t < 4; ++t) {
        qt[m][t] = mfma32(wq[m], xb[t], qt[m][t]);  // [c][tok]
        kt[m][t] = mfma32(wk[m], xb[t], kt[m][t]);
      }
  }
  u16x4 qp[2][4], kp[2][4];
#pragma unroll
  for (int m = 0; m < 2; ++m)
#pragma unroll
    for (int t = 0; t < 4; ++t) { qp[m][t] = pack4(qt[m][t]); kp[m][t] = pack4(kt[m][t]); }

  // ---- sub-pass B: V = x · Wv (re-read xs; qkv accs freed first) ----
  f32x4 vv[4][2];
#pragma unroll
  for (int t = 0; t < 4; ++t) { vv[t][0] = zero4; vv[t][1] = zero4; }
#pragma unroll
  for (int ks = 0; ks < 4; ++ks) {
    u16x8 xb[4];
#pragma unroll
    for (int t = 0; t < 4; ++t)
      xb[t] = *(const u16x8*)(xs + (t * 16 + q15) * 256 + ((ks * 64 + g * 16) ^ rs));
    const int kb = ks * 64 + g * 16;
    u16x8 wv[2];
#pragma unroll
    for (int n = 0; n < 2; ++n)
      wv[n] = *(const u16x8*)(wqb + (size_t)(h * 32 + n * 16 + q15 + 256) * 256 + kb);
#pragma unroll
    for (int t = 0; t < 4; ++t)
#pragma unroll
      for (int n = 0; n < 2; ++n)
        vv[t][n] = mfma32(xb[t], wv[n], vv[t][n]);  // [tok][d]
  }
  u16x4 vp[4][2];
#pragma unroll
  for (int t = 0; t < 4; ++t) { vp[t][0] = pack4(vv[t][0]); vp[t][1] = pack4(vv[t][1]); }

  // ---- S^T = K·Q^T + bias (bias loaded straight into accumulators, L2-hot) ----
  f32x4 st[4][4];
  const u16x4* bb = (const u16x4*)biasbf;
#pragma unroll
  for (int mk = 0; mk < 4; ++mk)
#pragma unroll
    for (int nq = 0; nq < 4; ++nq)
      st[mk][nq] = bf4up(bb[((h * 4 + mk) * 4 + nq) * 64 + lane]);
#pragma unroll
  for (int ks2 = 0; ks2 < 2; ++ks2)
#pragma unroll
    for (int mk = 0; mk < 4; ++mk)
#pragma unroll
      for (int nq = 0; nq < 4; ++nq)
        st[mk][nq] = mfma16(kp[ks2][mk], qp[ks2][nq], st[mk][nq]);

  // ---- softmax over keys (logits pre-scaled by log2e; no max-subtract needed) ----
  float rc[4];
#pragma unroll
  for (int nq = 0; nq < 4; ++nq) {
    float s = 0.f;
#pragma unroll
    for (int mk = 0; mk < 4; ++mk)
#pragma unroll
      for (int i = 0; i < 4; ++i) {
        float e = exp2f(st[mk][nq][i]);
        st[mk][nq][i] = e;
        s += e;
      }
    s += __shfl_xor(s, 16);
    s += __shfl_xor(s, 32);
    rc[nq] = __builtin_amdgcn_rcpf(s);
  }
  u16x4 pp[4][4];
#pragma unroll
  for (int mk = 0; mk < 4; ++mk)
#pragma unroll
    for (int nq = 0; nq < 4; ++nq) pp[mk][nq] = pack4(st[mk][nq]);

  // ---- out^T = V^T · P^T ----
  f32x4 ot[2][4];
#pragma unroll
  for (int md = 0; md < 2; ++md)
#pragma unroll
    for (int nq = 0; nq < 4; ++nq) ot[md][nq] = zero4;
#pragma unroll
  for (int ks = 0; ks < 4; ++ks)
#pragma unroll
    for (int md = 0; md < 2; ++md)
#pragma unroll
      for (int nq = 0; nq < 4; ++nq)
        ot[md][nq] = mfma16(vp[ks][md], pp[ks][nq], ot[md][nq]);

  // ---- stage attn-out bf16 into ao (own region; no WAR on xs) ----
#pragma unroll
  for (int md = 0; md < 2; ++md)
#pragma unroll
    for (int nq = 0; nq < 4; ++nq) {
      int tok = nq * 16 + q15;
      int cb = (h * 64 + md * 32 + g * 8) ^ rs;  // tok&7 == q15&7
      uint2 w2;
      w2.x = pk2n(ot[md][nq][0] * rc[nq], ot[md][nq][1] * rc[nq]);
      w2.y = pk2n(ot[md][nq][2] * rc[nq], ot[md][nq][3] * rc[nq]);
      *(uint2*)(ao + tok * 256 + cb) = w2;
    }

  // ---- prefetch proj weights/bias while waiting at the barrier ----
  u16x8 wp[4][2];
  const char* wpb = (const char*)wprojt;
#pragma unroll
  for (int ks = 0; ks < 4; ++ks)
#pragma unroll
    for (int n = 0; n < 2; ++n)
      wp[ks][n] = *(const u16x8*)(wpb + (size_t)(h * 32 + n * 16 + q15) * 256 + ks * 64 + g * 16);
  f32x4 bv[2];
#pragma unroll
  for (int n = 0; n < 2; ++n)
    bv[n] = *(const f32x4*)(bproj + h * 32 + n * 16 + g * 4);
  __syncthreads();  // C: attn-out complete

  // ---- proj GEMM (transposed): po = Wp^T · ao^T -> [ch][tok], f32x4 stores ----
  f32x4 po[2][4];
#pragma unroll
  for (int n = 0; n < 2; ++n)
#pragma unroll
    for (int t = 0; t < 4; ++t) po[n][t] = zero4;
#pragma unroll
  for (int ks = 0; ks < 4; ++ks) {
    u16x8 axb[4];
#pragma unroll
    for (int t = 0; t < 4; ++t)
      axb[t] = *(const u16x8*)(ao + (t * 16 + q15) * 256 + ((ks * 64 + g * 16) ^ rs));
#pragma unroll
    for (int n = 0; n < 2; ++n)
#pragma unroll
      for (int t = 0; t < 4; ++t)
        po[n][t] = mfma32(wp[ks][n], axb[t], po[n][t]);  // [ch][tok]
  }
  float* op = out + wbase;
#pragma unroll
  for (int n = 0; n < 2; ++n)
#pragma unroll
    for (int t = 0; t < 4; ++t) {
      f32x4 vs = po[n][t] + bv[n];
      *(f32x4*)(op + (size_t)(t * 16 + q15) * 128 + h * 32 + n * 16 + g * 4) = vs;
    }
}

extern "C" void kernel_launch(void* const* d_in, const int* in_sizes, int n_in,
                              void* d_out, int out_size, void* d_ws, size_t ws_size,
                              hipStream_t stream) {
  const float* x     = (const float*)d_in[0];
  const float* wqkv  = (const float*)d_in[1];
  const float* wproj = (const float*)d_in[2];
  const float* bproj = (const float*)d_in[3];
  const float* btab  = (const float*)d_in[4];
  char* ws = (char*)d_ws;
  unsigned short* wqkvt  = (unsigned short*)ws;             // 98304 B
  unsigned short* wprojt = (unsigned short*)(ws + 98304);   // 32768 B
  unsigned short* biasbf = (unsigned short*)(ws + 131072);  // 32768 B

  prep_kernel<<<320, 256, 0, stream>>>(wqkv, wproj, btab, wqkvt, wprojt, biasbf);
  attn_kernel<<<4096, 256, 0, stream>>>(x, wqkvt, wprojt, biasbf, bproj, (float*)d_out);
}